// Round 2
// baseline (76.598 us; speedup 1.0000x reference)
//
#include <hip/hip_runtime.h>
#include <math.h>

#define DIMS 4096
#define NSAMP 1024

__device__ __forceinline__ float softplus_f(float x) {
    // numerically stable: max(x,0) + log1p(exp(-|x|))
    return fmaxf(x, 0.0f) + log1pf(expf(-fabsf(x)));
}

// Kernel 1: one block. Computes invc2[D], w[D] into ws, and scalars
// ws[2D] = beta = sum b^2/c^2, ws[2D+1] = 2*sum(log c).
__global__ __launch_bounds__(256) void nagvac_prep(
        const float* __restrict__ b,
        const float* __restrict__ log_c,
        float* __restrict__ ws) {
    __shared__ float red[2][4];
    const int tid = threadIdx.x;            // 0..255
    float beta = 0.0f, slog = 0.0f;
    const float4* b4 = (const float4*)b;
    const float4* l4 = (const float4*)log_c;
    float4* ic4 = (float4*)ws;              // invc2 at ws[0..D-1]
    float4* w4  = (float4*)(ws + DIMS);     // w at ws[D..2D-1]

    for (int j = 0; j < DIMS / 4 / 256; ++j) {
        int v = j * 256 + tid;              // float4 index in [0, 1024)
        float4 bv = b4[v];
        float4 lv = l4[v];
        float bb[4] = {bv.x, bv.y, bv.z, bv.w};
        float ll[4] = {lv.x, lv.y, lv.z, lv.w};
        float ic[4], ww[4];
        #pragma unroll
        for (int k = 0; k < 4; ++k) {
            float c  = softplus_f(ll[k]) + 1e-4f;
            float i2 = 1.0f / (c * c);
            ic[k] = i2;
            ww[k] = bb[k] * i2;
            beta += bb[k] * bb[k] * i2;
            slog += logf(c);
        }
        ic4[v] = make_float4(ic[0], ic[1], ic[2], ic[3]);
        w4[v]  = make_float4(ww[0], ww[1], ww[2], ww[3]);
    }

    // wave64 butterfly then cross-wave via LDS
    #pragma unroll
    for (int off = 32; off > 0; off >>= 1) {
        beta += __shfl_down(beta, off);
        slog += __shfl_down(slog, off);
    }
    const int wave = tid >> 6, lane = tid & 63;
    if (lane == 0) { red[0][wave] = beta; red[1][wave] = slog; }
    __syncthreads();
    if (tid == 0) {
        float B = red[0][0] + red[0][1] + red[0][2] + red[0][3];
        float L = red[1][0] + red[1][1] + red[1][2] + red[1][3];
        ws[2 * DIMS]     = B;
        ws[2 * DIMS + 1] = 2.0f * L;
    }
}

// Kernel 2: one block per sample. quad = a1 - a2^2/(1+beta);
// out = -0.5*(quad + D*log(2pi) + 2*sum log c + log1p(beta)).
__global__ __launch_bounds__(256) void nagvac_logq(
        const float* __restrict__ theta,
        const float* __restrict__ mu,
        const float* __restrict__ ws,
        float* __restrict__ out) {
    __shared__ float red[2][4];
    const int s = blockIdx.x;
    const int tid = threadIdx.x;

    const float4* th = (const float4*)(theta + (size_t)s * DIMS);
    const float4* m4 = (const float4*)mu;
    const float4* ic4 = (const float4*)ws;
    const float4* w4  = (const float4*)(ws + DIMS);

    float a1 = 0.0f, a2 = 0.0f;
    #pragma unroll
    for (int j = 0; j < DIMS / 4 / 256; ++j) {
        int v = j * 256 + tid;
        float4 t = th[v];
        float4 m = m4[v];
        float4 ic = ic4[v];
        float4 w  = w4[v];
        float dx = t.x - m.x, dy = t.y - m.y, dz = t.z - m.z, dw = t.w - m.w;
        a1 += dx * dx * ic.x + dy * dy * ic.y + dz * dz * ic.z + dw * dw * ic.w;
        a2 += dx * w.x + dy * w.y + dz * w.z + dw * w.w;
    }

    #pragma unroll
    for (int off = 32; off > 0; off >>= 1) {
        a1 += __shfl_down(a1, off);
        a2 += __shfl_down(a2, off);
    }
    const int wave = tid >> 6, lane = tid & 63;
    if (lane == 0) { red[0][wave] = a1; red[1][wave] = a2; }
    __syncthreads();
    if (tid == 0) {
        float s1 = red[0][0] + red[0][1] + red[0][2] + red[0][3];
        float s2 = red[1][0] + red[1][1] + red[1][2] + red[1][3];
        float beta = ws[2 * DIMS];
        float tsl  = ws[2 * DIMS + 1];
        float quad = s1 - s2 * s2 / (1.0f + beta);
        const float LOG2PI = 1.8378770664093453f;
        out[s] = -0.5f * (quad + (float)DIMS * LOG2PI + tsl + log1pf(beta));
    }
}

extern "C" void kernel_launch(void* const* d_in, const int* in_sizes, int n_in,
                              void* d_out, int out_size, void* d_ws, size_t ws_size,
                              hipStream_t stream) {
    const float* theta = (const float*)d_in[0];
    const float* mu    = (const float*)d_in[1];
    const float* b     = (const float*)d_in[2];
    const float* log_c = (const float*)d_in[3];
    float* out = (float*)d_out;
    float* ws  = (float*)d_ws;

    nagvac_prep<<<1, 256, 0, stream>>>(b, log_c, ws);
    nagvac_logq<<<NSAMP, 256, 0, stream>>>(theta, mu, ws, out);
}

// Round 3
// 70.918 us; speedup vs baseline: 1.0801x; 1.0801x over previous
//
#include <hip/hip_runtime.h>
#include <math.h>

#define DIMS 4096
#define NSAMP 1024
#define SPB 2            // samples per block
#define TPB 256

// fast softplus: max(x,0) + log(1+exp(-|x|)) with HW exp/log (errors ~1ulp,
// contributes <1e-2 absolute to a ~8500-magnitude sum; threshold is 137)
__device__ __forceinline__ float fast_softplus(float x) {
    return fmaxf(x, 0.0f) + __logf(1.0f + __expf(-fabsf(x)));
}

// One fused kernel: each block owns SPB samples, recomputes per-dim
// invc2/w locally (no ws tables, no second launch), accumulates
//   a1_s = sum d_s^2 / c^2,  a2_s = sum d_s b / c^2,
//   beta = sum b^2 / c^2,    slog = sum log c
// then epilogue: quad = a1 - a2^2/(1+beta);
// out = -0.5*(quad + D*log2pi + 2*slog + log1p(beta)).
__global__ __launch_bounds__(TPB) void nagvac_fused(
        const float* __restrict__ theta,
        const float* __restrict__ mu,
        const float* __restrict__ b,
        const float* __restrict__ log_c,
        float* __restrict__ out) {
    __shared__ float red[6][4];
    const int tid = threadIdx.x;
    const int s0  = blockIdx.x * SPB;

    const float4* t0 = (const float4*)(theta + (size_t)s0 * DIMS);
    const float4* t1 = (const float4*)(theta + (size_t)(s0 + 1) * DIMS);
    const float4* m4 = (const float4*)mu;
    const float4* b4 = (const float4*)b;
    const float4* l4 = (const float4*)log_c;

    float a1_0 = 0.f, a2_0 = 0.f, a1_1 = 0.f, a2_1 = 0.f;
    float beta = 0.f, slog = 0.f;

    #pragma unroll
    for (int j = 0; j < DIMS / 4 / TPB; ++j) {
        const int v = j * TPB + tid;
        float4 ta = t0[v];
        float4 tb = t1[v];
        float4 m  = m4[v];
        float4 bv = b4[v];
        float4 lv = l4[v];
        float tt0[4] = {ta.x, ta.y, ta.z, ta.w};
        float tt1[4] = {tb.x, tb.y, tb.z, tb.w};
        float mm[4]  = {m.x, m.y, m.z, m.w};
        float bb[4]  = {bv.x, bv.y, bv.z, bv.w};
        float ll[4]  = {lv.x, lv.y, lv.z, lv.w};
        #pragma unroll
        for (int k = 0; k < 4; ++k) {
            float c  = fast_softplus(ll[k]) + 1e-4f;
            float i2 = __builtin_amdgcn_rcpf(c * c);   // ~1ulp reciprocal
            float w  = bb[k] * i2;
            beta += bb[k] * w;
            slog += __logf(c);
            float d0 = tt0[k] - mm[k];
            float d1 = tt1[k] - mm[k];
            a1_0 = fmaf(d0 * d0, i2, a1_0);
            a2_0 = fmaf(d0, w, a2_0);
            a1_1 = fmaf(d1 * d1, i2, a1_1);
            a2_1 = fmaf(d1, w, a2_1);
        }
    }

    // 6-value wave64 butterfly, then cross-wave via LDS
    float vals[6] = {a1_0, a2_0, a1_1, a2_1, beta, slog};
    #pragma unroll
    for (int r = 0; r < 6; ++r) {
        float v = vals[r];
        #pragma unroll
        for (int off = 32; off > 0; off >>= 1) v += __shfl_down(v, off);
        vals[r] = v;
    }
    const int wave = tid >> 6, lane = tid & 63;
    if (lane == 0) {
        #pragma unroll
        for (int r = 0; r < 6; ++r) red[r][wave] = vals[r];
    }
    __syncthreads();

    if (tid < SPB) {
        float A1 = red[2 * tid + 0][0] + red[2 * tid + 0][1]
                 + red[2 * tid + 0][2] + red[2 * tid + 0][3];
        float A2 = red[2 * tid + 1][0] + red[2 * tid + 1][1]
                 + red[2 * tid + 1][2] + red[2 * tid + 1][3];
        float B  = red[4][0] + red[4][1] + red[4][2] + red[4][3];
        float SL = red[5][0] + red[5][1] + red[5][2] + red[5][3];
        float quad = A1 - A2 * A2 / (1.0f + B);
        const float LOG2PI = 1.8378770664093453f;
        out[s0 + tid] = -0.5f * (quad + (float)DIMS * LOG2PI
                                 + 2.0f * SL + log1pf(B));
    }
}

extern "C" void kernel_launch(void* const* d_in, const int* in_sizes, int n_in,
                              void* d_out, int out_size, void* d_ws, size_t ws_size,
                              hipStream_t stream) {
    const float* theta = (const float*)d_in[0];
    const float* mu    = (const float*)d_in[1];
    const float* b     = (const float*)d_in[2];
    const float* log_c = (const float*)d_in[3];
    float* out = (float*)d_out;

    nagvac_fused<<<NSAMP / SPB, TPB, 0, stream>>>(theta, mu, b, log_c, out);
}